// Round 6
// baseline (516.142 us; speedup 1.0000x reference)
//
#include <hip/hip_runtime.h>
#include <math.h>

#define NB 512
#define NN 256
#define NCACHE 56
#define RSTRIDE 260   // LDS row stride in floats: %4==0 (aligned float4), bank-spread
#define LAP_INF 1e30f

// ws layout: flag @0, Pt @8192
#define WS_PT_OFF 8192

// ---------------------------------------------------------------------------
// pad_mask layout detection: flag = 1 (int32), 2 (float32), 0 (bytes/bool8).
// Reads only the first 131072 bytes (in-bounds under every layout).
// ---------------------------------------------------------------------------
__global__ __launch_bounds__(1024)
void detect_kernel(const unsigned int* __restrict__ pw, int* __restrict__ flag) {
  __shared__ int notInt, notFloat;
  if (threadIdx.x == 0) { notInt = 0; notFloat = 0; }
  __syncthreads();
  int li = 0, lf = 0;
  for (int t = threadIdx.x; t < 32768; t += 1024) {
    unsigned int w = pw[t];
    if (w > 1u) li = 1;
    if (w != 0u && w != 0x3F800000u) lf = 1;
  }
  if (li) atomicOr(&notInt, 1);
  if (lf) atomicOr(&notFloat, 1);
  __syncthreads();
  if (threadIdx.x == 0) flag[0] = (!notInt) ? 1 : ((!notFloat) ? 2 : 0);
}

// ---------------------------------------------------------------------------
// DPP wave64 u32 min (VALU-rate) + order/equality-preserving f32<->u32 map.
// ---------------------------------------------------------------------------
template <int CTRL>
__device__ __forceinline__ unsigned dpp_min_step(unsigned x) {
  unsigned y = (unsigned)__builtin_amdgcn_update_dpp((int)x, (int)x, CTRL, 0xF, 0xF, false);
  return y < x ? y : x;
}
__device__ __forceinline__ unsigned wave_min_u32(unsigned x) {
  x = dpp_min_step<0xB1>(x);   // quad_perm [1,0,3,2]
  x = dpp_min_step<0x4E>(x);   // quad_perm [2,3,0,1]
  x = dpp_min_step<0x141>(x);  // row_half_mirror
  x = dpp_min_step<0x140>(x);  // row_mirror
  x = dpp_min_step<0x142>(x);  // row_bcast15
  x = dpp_min_step<0x143>(x);  // row_bcast31
  return (unsigned)__builtin_amdgcn_readlane((int)x, 63);
}
__device__ __forceinline__ unsigned f2o(float f) {
  unsigned x = __float_as_uint(f);
  return x ^ ((unsigned)((int)x >> 31) | 0x80000000u);
}
__device__ __forceinline__ float o2f(unsigned m) {
  unsigned x = (m & 0x80000000u) ? (m & 0x7FFFFFFFu) : ~m;
  return __uint_as_float(x);
}
__device__ __forceinline__ int sel4(const int a[4], int s) {
  return (s == 0) ? a[0] : (s == 1) ? a[1] : (s == 2) ? a[2] : a[3];
}
__device__ __forceinline__ void set4(int a[4], int s, int v) {
  if (s == 0) a[0] = v; else if (s == 1) a[1] = v;
  else if (s == 2) a[2] = v; else a[3] = v;
}

// ---------------------------------------------------------------------------
// One wave64 per batch.
// Phase 1 (lane-parallel row reduction): lane L scans rows {L, L+64, L+128,
// L+192} of cost^T = columns of costs. At fixed j all 64 lanes read 256
// contiguous floats (coalesced). Each lane tracks (min, first-argmin) per row
// and, in passing, stages rows <NCACHE into LDS (bank-padded) and rows
// [NCACHE, n_k) into Pt (global scratch) for phase 2's coalesced reads.
// Conflict walk: serial but trivial (registers + readlane, no row scans).
// Phase 2: JV shortest augmenting path for leftover free rows, exact
// reference float op order. Lane L owns cols 4L..4L+3 (v, shortest, pathrow,
// SC, row4col) and rows 4L..4L+3 (u, SR, col4row) in registers.
// Final assignment equals the reference's (unique optimum; validated R2-R4).
// ---------------------------------------------------------------------------
__global__ __launch_bounds__(64)
void lap_kernel(const float* __restrict__ costs, const void* __restrict__ pm,
                const int* __restrict__ flag, float* __restrict__ Pt,
                int* __restrict__ out, int useT) {
  const int k = blockIdx.x;
  const int lane = threadIdx.x;

  __shared__ __align__(16) float rowCache[NCACHE * RSTRIDE];
  __shared__ float shortestL[NN];
  __shared__ float rowminL[NN];
  __shared__ int rowargL[NN];
  __shared__ int freeRowsL[NN];
  __shared__ unsigned char used[NN];

  const float* costK = costs + ((size_t)k << 16);
  float* PtK = Pt + ((size_t)k << 16);

  // ---- n_k = popcount(pad_mask[k]) under detected layout ----
  const int fl = flag[0];
  int cnt4 = 0;
  if (fl == 1) {
    const int* p = ((const int*)pm) + k * NN;
#pragma unroll
    for (int q = 0; q < 4; ++q) cnt4 += (p[lane * 4 + q] != 0);
  } else if (fl == 2) {
    const float* p = ((const float*)pm) + k * NN;
#pragma unroll
    for (int q = 0; q < 4; ++q) cnt4 += (p[lane * 4 + q] != 0.0f);
  } else {
    const unsigned char* p = ((const unsigned char*)pm) + k * NN;
#pragma unroll
    for (int q = 0; q < 4; ++q) cnt4 += (p[lane * 4 + q] != 0);
  }
#pragma unroll
  for (int off = 32; off > 0; off >>= 1) cnt4 += __shfl_down(cnt4, off);
  const int n_k = __shfl(cnt4, 0);

  // ---- phase 1: lane-parallel row scans (coalesced) + staging ----
  float bv0 = LAP_INF, bv1 = LAP_INF, bv2 = LAP_INF, bv3 = LAP_INF;
  int bi0 = -1, bi1 = -1, bi2 = -1, bi3 = -1;
  const int r0 = lane, r1 = lane + 64, r2 = lane + 128, r3 = lane + 192;
  for (int j = 0; j < NN; ++j) {
    const float* cj = costK + (size_t)j * NN;
    float x0 = cj[r0], x1 = cj[r1], x2 = cj[r2], x3 = cj[r3];
    x0 = isfinite(x0) ? x0 : 1e6f;
    x1 = isfinite(x1) ? x1 : 1e6f;
    x2 = isfinite(x2) ? x2 : 1e6f;
    x3 = isfinite(x3) ? x3 : 1e6f;
    if (lane < NCACHE) rowCache[lane * RSTRIDE + j] = x0;
    if (useT) {
      if (r0 >= NCACHE && r0 < n_k) PtK[(size_t)r0 * NN + j] = x0;
      if (r1 < n_k) PtK[(size_t)r1 * NN + j] = x1;
      if (r2 < n_k) PtK[(size_t)r2 * NN + j] = x2;
      if (r3 < n_k) PtK[(size_t)r3 * NN + j] = x3;
    }
    if (x0 < bv0) { bv0 = x0; bi0 = j; }   // strict < keeps first index
    if (x1 < bv1) { bv1 = x1; bi1 = j; }
    if (x2 < bv2) { bv2 = x2; bi2 = j; }
    if (x3 < bv3) { bv3 = x3; bi3 = j; }
  }
  rowminL[r0] = bv0; rowargL[r0] = bi0;
  rowminL[r1] = bv1; rowargL[r1] = bi1;
  rowminL[r2] = bv2; rowargL[r2] = bi2;
  rowminL[r3] = bv3; rowargL[r3] = bi3;
  if (useT) __threadfence();  // order Pt stores before phase-2 reads
  __syncthreads();            // also drains vmcnt (measured compiler behavior)

  // redistribute: row r -> lane r>>2, slot r&3
  float uu[4];
  int ja[4];
#pragma unroll
  for (int q = 0; q < 4; ++q) {
    const int row = lane * 4 + q;
    uu[q] = (row < n_k) ? rowminL[row] : 0.f;  // u[r] = row min (dual-feasible)
    ja[q] = rowargL[row];
  }

  float vv[4] = {0.f, 0.f, 0.f, 0.f};
  int r4c[4] = {-1, -1, -1, -1};   // row4col, col-indexed
  int c4r[4] = {-1, -1, -1, -1};   // col4row, row-indexed
  int nfree = 0;                    // wave-uniform

  // ---- serial conflict walk (no row scans) ----
  for (int r = 0; r < n_k; ++r) {
    const int js = __builtin_amdgcn_readlane(sel4(ja, r & 3), r >> 2);
    const int occ = __builtin_amdgcn_readlane(sel4(r4c, js & 3), js >> 2);
    if (occ < 0) {
      if (lane == (js >> 2)) set4(r4c, js & 3, r);
      if (lane == (r >> 2)) set4(c4r, r & 3, js);
    } else {
      if (lane == 0) freeRowsL[nfree] = r;
      nfree++;
    }
  }
  __syncthreads();  // freeRowsL visible

  // ---- phase 2: shortest augmenting path for leftover free rows ----
  for (int t = 0; t < nfree; ++t) {
    const int cur = freeRowsL[t];
    float sh[4] = {LAP_INF, LAP_INF, LAP_INF, LAP_INF};
    int pr[4] = {-1, -1, -1, -1};
    unsigned scm = 0;  // SC bits, this lane's 4 cols
    unsigned srm = 0;  // SR bits, this lane's 4 rows
    float minval = 0.f;
    int i = cur, sink = -1;

    while (sink < 0) {
      const int islot = i & 3, iowner = i >> 2;
      if (lane == iowner) srm |= (1u << islot);
      const float su = (islot == 0) ? uu[0] : (islot == 1) ? uu[1]
                     : (islot == 2) ? uu[2] : uu[3];
      const float ui = __int_as_float(
          __builtin_amdgcn_readlane(__float_as_int(su), iowner));

      float cc[4];
      if (i < NCACHE) {
        const float4 rv = *(const float4*)(&rowCache[i * RSTRIDE + lane * 4]);
        cc[0] = rv.x; cc[1] = rv.y; cc[2] = rv.z; cc[3] = rv.w;
      } else if (useT) {
        const float4 rv = *(const float4*)(PtK + (size_t)i * NN + lane * 4);
        cc[0] = rv.x; cc[1] = rv.y; cc[2] = rv.z; cc[3] = rv.w;
      } else {
#pragma unroll
        for (int q = 0; q < 4; ++q) {
          float x = costK[(size_t)(lane * 4 + q) * NN + i];
          cc[q] = isfinite(x) ? x : 1e6f;
        }
      }

      unsigned lbv = 0xFFFFFFFFu;
      int lbq = 0;
#pragma unroll
      for (int q = 0; q < 4; ++q) {
        // exact reference order: ((minval + cost) - u[i]) - v[j]
        float r = minval + cc[q];
        r = r - ui;
        r = r - vv[q];
        const bool sc = (scm >> q) & 1u;
        if (!sc && r < sh[q]) { sh[q] = r; pr[q] = i; }
        const unsigned m = sc ? 0xFFFFFFFFu : f2o(sh[q]);
        if (m < lbv) { lbv = m; lbq = q; }
      }
      const unsigned gv = wave_min_u32(lbv);
      minval = o2f(gv);
      const unsigned long long cmask = __ballot(lbv == gv);
      const int owner = __ffsll((unsigned long long)cmask) - 1;
      const int js = (owner << 2) + __builtin_amdgcn_readlane(lbq, owner);
      if (lane == owner) scm |= (1u << lbq);
      const int nxt = __builtin_amdgcn_readlane(sel4(r4c, js & 3), owner);
      if (nxt < 0) sink = js; else i = nxt;
    }

    // publish shortest for the dual update's dynamic gather
#pragma unroll
    for (int q = 0; q < 4; ++q) shortestL[lane * 4 + q] = sh[q];
    __syncthreads();

    // ---- dual updates (Crouse 2016) ----
#pragma unroll
    for (int q = 0; q < 4; ++q) {
      if ((srm >> q) & 1u) {
        const int row = lane * 4 + q;
        if (row == cur) uu[q] = uu[q] + minval;
        else uu[q] = uu[q] + (minval - shortestL[c4r[q]]);
      }
      if ((scm >> q) & 1u) vv[q] = vv[q] - (minval - sh[q]);
    }

    // ---- augment along alternating path: pure registers ----
    int j = sink;
    bool done = false;
    while (!done) {
      const int pi = __builtin_amdgcn_readlane(sel4(pr, j & 3), j >> 2);
      if (lane == (j >> 2)) set4(r4c, j & 3, pi);
      const int jn = __builtin_amdgcn_readlane(sel4(c4r, pi & 3), pi >> 2);
      if (lane == (pi >> 2)) set4(c4r, pi & 3, j);
      done = (pi == cur);
      j = jn;
    }
    __syncthreads();  // shortestL reused next path
  }

  // ---- output: valid rows get col4row; padded rows get unused cols asc ----
  for (int t = lane; t < NN; t += 64) used[t] = 0;
  __syncthreads();
#pragma unroll
  for (int q = 0; q < 4; ++q) {
    const int row = lane * 4 + q;
    if (row < n_k) used[c4r[q]] = 1;
  }
  __syncthreads();
  int* outK = out + k * NN;
#pragma unroll
  for (int q = 0; q < 4; ++q) {
    const int row = lane * 4 + q;
    if (row < n_k) outK[row] = c4r[q];
  }
  if (lane == 0) {
    int pos = n_k;
    for (int c = 0; c < NN; ++c)
      if (!used[c]) outK[pos++] = c;
  }
}

extern "C" void kernel_launch(void* const* d_in, const int* in_sizes, int n_in,
                              void* d_out, int out_size, void* d_ws, size_t ws_size,
                              hipStream_t stream) {
  const float* costs = (const float*)d_in[0];
  const void* pm = d_in[1];
  int* out = (int*)d_out;

  int* flag = (int*)d_ws;
  float* Pt = (float*)((char*)d_ws + WS_PT_OFF);
  const size_t need = WS_PT_OFF + (size_t)NB * NN * NN * sizeof(float);
  const int useT = (ws_size >= need) ? 1 : 0;

  detect_kernel<<<1, 1024, 0, stream>>>((const unsigned int*)pm, flag);
  lap_kernel<<<NB, 64, 0, stream>>>(costs, pm, flag, Pt, out, useT);
}

// Round 7
// 406.641 us; speedup vs baseline: 1.2693x; 1.2693x over previous
//
#include <hip/hip_runtime.h>
#include <math.h>

#define NB 512
#define NN 256
#define NCACHE 60
#define LAP_INF 1e30f

// ws layout (mode 2): flag@0, nk@1024, rmv@8192, rma@8192+512K, Pt@8192+1M
#define WS_NK_OFF 1024
#define WS_RMV_OFF 8192
#define WS_RMA_OFF (8192 + 512 * 1024)
#define WS_PT_OFF_FULL (8192 + 1024 * 1024)
#define WS_PT_OFF_R4 8192

// ---------------------------------------------------------------------------
// pad_mask layout detection: flag = 1 (int32), 2 (float32), 0 (bytes/bool8).
// ---------------------------------------------------------------------------
__global__ __launch_bounds__(1024)
void detect_kernel(const unsigned int* __restrict__ pw, int* __restrict__ flag) {
  __shared__ int notInt, notFloat;
  if (threadIdx.x == 0) { notInt = 0; notFloat = 0; }
  __syncthreads();
  int li = 0, lf = 0;
  for (int t = threadIdx.x; t < 32768; t += 1024) {
    unsigned int w = pw[t];
    if (w > 1u) li = 1;
    if (w != 0u && w != 0x3F800000u) lf = 1;
  }
  if (li) atomicOr(&notInt, 1);
  if (lf) atomicOr(&notFloat, 1);
  __syncthreads();
  if (threadIdx.x == 0) flag[0] = (!notInt) ? 1 : ((!notFloat) ? 2 : 0);
}

// ---------------------------------------------------------------------------
// n_k[k] = popcount(pad_mask[k]) under detected layout. One wave per batch.
// ---------------------------------------------------------------------------
__global__ __launch_bounds__(64)
void nk_kernel(const void* __restrict__ pm, const int* __restrict__ flag,
               int* __restrict__ nk) {
  const int k = blockIdx.x;
  const int lane = threadIdx.x;
  const int fl = flag[0];
  int cnt4 = 0;
  if (fl == 1) {
    const int* p = ((const int*)pm) + k * NN;
#pragma unroll
    for (int q = 0; q < 4; ++q) cnt4 += (p[lane * 4 + q] != 0);
  } else if (fl == 2) {
    const float* p = ((const float*)pm) + k * NN;
#pragma unroll
    for (int q = 0; q < 4; ++q) cnt4 += (p[lane * 4 + q] != 0.0f);
  } else {
    const unsigned char* p = ((const unsigned char*)pm) + k * NN;
#pragma unroll
    for (int q = 0; q < 4; ++q) cnt4 += (p[lane * 4 + q] != 0);
  }
#pragma unroll
  for (int off = 32; off > 0; off >>= 1) cnt4 += __shfl_down(cnt4, off);
  if (lane == 0) nk[k] = cnt4;
}

// ---------------------------------------------------------------------------
// Transpose + sanitize ONLY rows i < max(n_k[k], NCACHE) of Pt.
// ---------------------------------------------------------------------------
__global__ __launch_bounds__(256)
void transpose_kernel(const float* __restrict__ in, float* __restrict__ out,
                      const int* __restrict__ nk) {
  const int k = blockIdx.z;
  const int i0 = blockIdx.x * 32;
  int bnd = nk[k];
  bnd = bnd > NCACHE ? bnd : NCACHE;
  if (i0 >= bnd) return;
  __shared__ float tile[32][33];
  const float* A = in + ((size_t)k << 16);
  float* Bp = out + ((size_t)k << 16);
  const int tx = threadIdx.x, ty = threadIdx.y;
  const int j0 = blockIdx.y * 32;
#pragma unroll
  for (int r = 0; r < 32; r += 8) {
    float x = A[(size_t)(j0 + ty + r) * NN + (i0 + tx)];
    tile[ty + r][tx] = isfinite(x) ? x : 1e6f;
  }
  __syncthreads();
#pragma unroll
  for (int r = 0; r < 32; r += 8) {
    Bp[(size_t)(i0 + ty + r) * NN + (j0 + tx)] = tile[tx][ty + r];
  }
}

// ---------------------------------------------------------------------------
// DPP wave64 u32 min (VALU-rate) + order/equality-preserving f32<->u32 map.
// ---------------------------------------------------------------------------
template <int CTRL>
__device__ __forceinline__ unsigned dpp_min_step(unsigned x) {
  unsigned y = (unsigned)__builtin_amdgcn_update_dpp((int)x, (int)x, CTRL, 0xF, 0xF, false);
  return y < x ? y : x;
}
__device__ __forceinline__ unsigned wave_min_u32(unsigned x) {
  x = dpp_min_step<0xB1>(x);   // quad_perm [1,0,3,2]
  x = dpp_min_step<0x4E>(x);   // quad_perm [2,3,0,1]
  x = dpp_min_step<0x141>(x);  // row_half_mirror
  x = dpp_min_step<0x140>(x);  // row_mirror
  x = dpp_min_step<0x142>(x);  // row_bcast15
  x = dpp_min_step<0x143>(x);  // row_bcast31
  return (unsigned)__builtin_amdgcn_readlane((int)x, 63);
}
__device__ __forceinline__ unsigned f2o(float f) {
  unsigned x = __float_as_uint(f);
  return x ^ ((unsigned)((int)x >> 31) | 0x80000000u);
}
__device__ __forceinline__ float o2f(unsigned m) {
  unsigned x = (m & 0x80000000u) ? (m & 0x7FFFFFFFu) : ~m;
  return __uint_as_float(x);
}
__device__ __forceinline__ int sel4(const int a[4], int s) {
  return (s == 0) ? a[0] : (s == 1) ? a[1] : (s == 2) ? a[2] : a[3];
}
__device__ __forceinline__ void set4(int a[4], int s, int v) {
  if (s == 0) a[0] = v; else if (s == 1) a[1] = v;
  else if (s == 2) a[2] = v; else a[3] = v;
}
__device__ __forceinline__ void setf4(float a[4], int s, float v) {
  if (s == 0) a[0] = v; else if (s == 1) a[1] = v;
  else if (s == 2) a[2] = v; else a[3] = v;
}

// ---------------------------------------------------------------------------
// Per-row (min, first-argmin) of Pt, one wave per row, fully parallel.
// Same values & tie-breaks as the in-lap greedy scan it replaces.
// ---------------------------------------------------------------------------
__global__ __launch_bounds__(256)
void rowmin_kernel(const float* __restrict__ Pt, const int* __restrict__ nk,
                   float* __restrict__ rmv, int* __restrict__ rma) {
  const int k = blockIdx.x;
  const int wid = threadIdx.x >> 6, lane = threadIdx.x & 63;
  const int row = blockIdx.y * 4 + wid;
  int bnd = nk[k];
  bnd = bnd > NCACHE ? bnd : NCACHE;
  if (row >= bnd) return;  // per-wave uniform exit; no barriers below
  const float4 rv = *(const float4*)(Pt + ((size_t)k << 16) + (size_t)row * NN + lane * 4);
  float bv = rv.x; int bj = lane * 4;
  if (rv.y < bv) { bv = rv.y; bj = lane * 4 + 1; }  // strict < keeps first idx
  if (rv.z < bv) { bv = rv.z; bj = lane * 4 + 2; }
  if (rv.w < bv) { bv = rv.w; bj = lane * 4 + 3; }
  const unsigned m = f2o(bv);
  const unsigned g = wave_min_u32(m);
  const unsigned long long cm = __ballot(m == g);
  const int owner = __ffsll(cm) - 1;  // lowest lane = first index
  const int ja = __builtin_amdgcn_readlane(bj, owner);
  if (lane == 0) {
    rmv[k * NN + row] = o2f(g);
    rma[k * NN + row] = ja;
  }
}

// ---------------------------------------------------------------------------
// One wave64 per batch. Lane L owns cols 4L..4L+3 (v, shortest, pathrow, SC,
// row4col) and rows 4L..4L+3 (u, SR, col4row) in registers.
// mode 2: greedy init from precomputed rmv/rma (conflict walk only).
// mode 1: R4-style in-lap greedy scan (LDS/Pt rows).  mode 0: strided direct.
// Phase 2: JV shortest augmenting path, exact reference float op order.
// ---------------------------------------------------------------------------
__global__ __launch_bounds__(64)
void lap_kernel(const float* __restrict__ costs, const void* __restrict__ pm,
                const int* __restrict__ flag, const int* __restrict__ nkArr,
                const float* __restrict__ rmv, const int* __restrict__ rma,
                const float* __restrict__ Pt, int* __restrict__ out, int mode) {
  const int k = blockIdx.x;
  const int lane = threadIdx.x;

  __shared__ __align__(16) float rowCache[NCACHE][NN];
  __shared__ float shortestL[NN];
  __shared__ int freeRowsL[NN];
  __shared__ unsigned char used[NN];

  const float* PtK = Pt + ((size_t)k << 16);
  const float* costK = costs + ((size_t)k << 16);

  int n_k;
  if (mode >= 1) {
    n_k = nkArr[k];
  } else {
    const int fl = flag[0];
    int cnt4 = 0;
    if (fl == 1) {
      const int* p = ((const int*)pm) + k * NN;
#pragma unroll
      for (int q = 0; q < 4; ++q) cnt4 += (p[lane * 4 + q] != 0);
    } else if (fl == 2) {
      const float* p = ((const float*)pm) + k * NN;
#pragma unroll
      for (int q = 0; q < 4; ++q) cnt4 += (p[lane * 4 + q] != 0.0f);
    } else {
      const unsigned char* p = ((const unsigned char*)pm) + k * NN;
#pragma unroll
      for (int q = 0; q < 4; ++q) cnt4 += (p[lane * 4 + q] != 0);
    }
#pragma unroll
    for (int off = 32; off > 0; off >>= 1) cnt4 += __shfl_down(cnt4, off);
    n_k = __shfl(cnt4, 0);
  }

  // ---- fill LDS row cache ----
  if (mode >= 1) {
    const float4* s4 = (const float4*)PtK;
    float4* c4 = (float4*)rowCache;
    for (int t = lane; t < NCACHE * (NN / 4); t += 64) c4[t] = s4[t];
  } else {
    for (int e = lane; e < NCACHE * NN; e += 64) {
      const int i = e >> 8, j = e & 255;
      float x = costK[(size_t)j * NN + i];
      rowCache[i][j] = isfinite(x) ? x : 1e6f;
    }
  }

  float vv[4] = {0.f, 0.f, 0.f, 0.f};
  float uu[4] = {0.f, 0.f, 0.f, 0.f};
  int r4c[4] = {-1, -1, -1, -1};   // row4col, col-indexed
  int c4r[4] = {-1, -1, -1, -1};   // col4row, row-indexed
  int ja[4] = {-1, -1, -1, -1};    // greedy argmin per owned row
  int nfree = 0;                    // wave-uniform
  __syncthreads();

  // ---- phase 1: greedy row-reduction init ----
  if (mode == 2) {
    // precomputed minima: lane loads its 4 rows' (min, argmin)
    const float4 mv = *(const float4*)(rmv + k * NN + lane * 4);
    const int4 av = *(const int4*)(rma + k * NN + lane * 4);
    uu[0] = mv.x; uu[1] = mv.y; uu[2] = mv.z; uu[3] = mv.w;
    ja[0] = av.x; ja[1] = av.y; ja[2] = av.z; ja[3] = av.w;
#pragma unroll
    for (int q = 0; q < 4; ++q)
      if (lane * 4 + q >= n_k) uu[q] = 0.f;
    // serial conflict walk (registers + readlane only)
    for (int r = 0; r < n_k; ++r) {
      const int js = __builtin_amdgcn_readlane(sel4(ja, r & 3), r >> 2);
      const int occ = __builtin_amdgcn_readlane(sel4(r4c, js & 3), js >> 2);
      if (occ < 0) {
        if (lane == (js >> 2)) set4(r4c, js & 3, r);
        if (lane == (r >> 2)) set4(c4r, r & 3, js);
      } else {
        if (lane == 0) freeRowsL[nfree] = r;
        nfree++;
      }
    }
  } else {
    // in-lap greedy scan (R4 behavior)
    float4 carry = {0.f, 0.f, 0.f, 0.f};
    for (int r = 0; r < n_k; ++r) {
      float cc[4];
      if (r < NCACHE) {
        const float4 rv = *(const float4*)(&rowCache[r][lane * 4]);
        cc[0] = rv.x; cc[1] = rv.y; cc[2] = rv.z; cc[3] = rv.w;
      } else if (mode >= 1) {
        cc[0] = carry.x; cc[1] = carry.y; cc[2] = carry.z; cc[3] = carry.w;
      } else {
#pragma unroll
        for (int q = 0; q < 4; ++q) {
          float x = costK[(size_t)(lane * 4 + q) * NN + r];
          cc[q] = isfinite(x) ? x : 1e6f;
        }
      }
      if (mode >= 1 && r + 1 >= NCACHE && r + 1 < n_k)
        carry = *(const float4*)(PtK + (size_t)(r + 1) * NN + lane * 4);

      unsigned lbv = 0xFFFFFFFFu;
      int lbq = 0;
#pragma unroll
      for (int q = 0; q < 4; ++q) {
        const unsigned m = f2o(cc[q]);
        if (m < lbv) { lbv = m; lbq = q; }
      }
      const unsigned gv = wave_min_u32(lbv);
      const unsigned long long cmask = __ballot(lbv == gv);
      const int owner = __ffsll((unsigned long long)cmask) - 1;
      const int js = (owner << 2) + __builtin_amdgcn_readlane(lbq, owner);
      if (lane == (r >> 2)) setf4(uu, r & 3, o2f(gv));
      const int occ = __builtin_amdgcn_readlane(sel4(r4c, js & 3), owner);
      if (occ < 0) {
        if (lane == owner) set4(r4c, js & 3, r);
        if (lane == (r >> 2)) set4(c4r, r & 3, js);
      } else {
        if (lane == 0) freeRowsL[nfree] = r;
        nfree++;
      }
    }
  }
  __syncthreads();  // freeRowsL visible

  // ---- phase 2: shortest augmenting path for leftover free rows ----
  for (int t = 0; t < nfree; ++t) {
    const int cur = freeRowsL[t];
    float sh[4] = {LAP_INF, LAP_INF, LAP_INF, LAP_INF};
    int pr[4] = {-1, -1, -1, -1};
    unsigned scm = 0;  // SC bits, this lane's 4 cols
    unsigned srm = 0;  // SR bits, this lane's 4 rows
    float minval = 0.f;
    int i = cur, sink = -1;

    while (sink < 0) {
      const int islot = i & 3, iowner = i >> 2;
      if (lane == iowner) srm |= (1u << islot);
      const float su = (islot == 0) ? uu[0] : (islot == 1) ? uu[1]
                     : (islot == 2) ? uu[2] : uu[3];
      const float ui = __int_as_float(
          __builtin_amdgcn_readlane(__float_as_int(su), iowner));

      float cc[4];
      if (i < NCACHE) {
        const float4 rv = *(const float4*)(&rowCache[i][lane * 4]);
        cc[0] = rv.x; cc[1] = rv.y; cc[2] = rv.z; cc[3] = rv.w;
      } else if (mode >= 1) {
        const float4 rv = *(const float4*)(PtK + (size_t)i * NN + lane * 4);
        cc[0] = rv.x; cc[1] = rv.y; cc[2] = rv.z; cc[3] = rv.w;
      } else {
#pragma unroll
        for (int q = 0; q < 4; ++q) {
          float x = costK[(size_t)(lane * 4 + q) * NN + i];
          cc[q] = isfinite(x) ? x : 1e6f;
        }
      }

      unsigned lbv = 0xFFFFFFFFu;
      int lbq = 0;
#pragma unroll
      for (int q = 0; q < 4; ++q) {
        // exact reference order: ((minval + cost) - u[i]) - v[j]
        float r = minval + cc[q];
        r = r - ui;
        r = r - vv[q];
        const bool sc = (scm >> q) & 1u;
        if (!sc && r < sh[q]) { sh[q] = r; pr[q] = i; }
        const unsigned m = sc ? 0xFFFFFFFFu : f2o(sh[q]);
        if (m < lbv) { lbv = m; lbq = q; }
      }
      const unsigned gv = wave_min_u32(lbv);
      minval = o2f(gv);
      const unsigned long long cmask = __ballot(lbv == gv);
      const int owner = __ffsll((unsigned long long)cmask) - 1;
      const int js = (owner << 2) + __builtin_amdgcn_readlane(lbq, owner);
      if (lane == owner) scm |= (1u << lbq);
      const int nxt = __builtin_amdgcn_readlane(sel4(r4c, js & 3), owner);
      if (nxt < 0) sink = js; else i = nxt;
    }

    // publish shortest for the dual update's dynamic gather
#pragma unroll
    for (int q = 0; q < 4; ++q) shortestL[lane * 4 + q] = sh[q];
    __syncthreads();

    // ---- dual updates (Crouse 2016) ----
#pragma unroll
    for (int q = 0; q < 4; ++q) {
      if ((srm >> q) & 1u) {
        const int row = lane * 4 + q;
        if (row == cur) uu[q] = uu[q] + minval;
        else uu[q] = uu[q] + (minval - shortestL[c4r[q]]);
      }
      if ((scm >> q) & 1u) vv[q] = vv[q] - (minval - sh[q]);
    }

    // ---- augment along alternating path: pure registers ----
    int j = sink;
    bool done = false;
    while (!done) {
      const int pi = __builtin_amdgcn_readlane(sel4(pr, j & 3), j >> 2);
      if (lane == (j >> 2)) set4(r4c, j & 3, pi);
      const int jn = __builtin_amdgcn_readlane(sel4(c4r, pi & 3), pi >> 2);
      if (lane == (pi >> 2)) set4(c4r, pi & 3, j);
      done = (pi == cur);
      j = jn;
    }
    __syncthreads();  // shortestL reused next path
  }

  // ---- output: valid rows get col4row; padded rows get unused cols asc ----
  for (int t = lane; t < NN; t += 64) used[t] = 0;
  __syncthreads();
#pragma unroll
  for (int q = 0; q < 4; ++q) {
    const int row = lane * 4 + q;
    if (row < n_k) used[c4r[q]] = 1;
  }
  __syncthreads();
  int* outK = out + k * NN;
#pragma unroll
  for (int q = 0; q < 4; ++q) {
    const int row = lane * 4 + q;
    if (row < n_k) outK[row] = c4r[q];
  }
  if (lane == 0) {
    int pos = n_k;
    for (int c = 0; c < NN; ++c)
      if (!used[c]) outK[pos++] = c;
  }
}

extern "C" void kernel_launch(void* const* d_in, const int* in_sizes, int n_in,
                              void* d_out, int out_size, void* d_ws, size_t ws_size,
                              hipStream_t stream) {
  const float* costs = (const float*)d_in[0];
  const void* pm = d_in[1];
  int* out = (int*)d_out;

  int* flag = (int*)d_ws;
  int* nk = (int*)((char*)d_ws + WS_NK_OFF);
  const size_t ptBytes = (size_t)NB * NN * NN * sizeof(float);

  int mode;
  float* rmv; int* rma; float* Pt;
  if (ws_size >= WS_PT_OFF_FULL + ptBytes) {
    mode = 2;
    rmv = (float*)((char*)d_ws + WS_RMV_OFF);
    rma = (int*)((char*)d_ws + WS_RMA_OFF);
    Pt = (float*)((char*)d_ws + WS_PT_OFF_FULL);
  } else if (ws_size >= WS_PT_OFF_R4 + ptBytes) {
    mode = 1;
    rmv = (float*)d_ws; rma = (int*)d_ws;
    Pt = (float*)((char*)d_ws + WS_PT_OFF_R4);
  } else {
    mode = 0;
    rmv = (float*)d_ws; rma = (int*)d_ws;
    Pt = (float*)costs;  // unused
  }

  detect_kernel<<<1, 1024, 0, stream>>>((const unsigned int*)pm, flag);
  nk_kernel<<<NB, 64, 0, stream>>>(pm, flag, nk);
  if (mode >= 1) {
    dim3 g(8, 8, NB), b(32, 8);
    transpose_kernel<<<g, b, 0, stream>>>(costs, Pt, nk);
  }
  if (mode == 2) {
    dim3 g(NB, 64);
    rowmin_kernel<<<g, 256, 0, stream>>>(Pt, nk, rmv, rma);
  }
  lap_kernel<<<NB, 64, 0, stream>>>(costs, pm, flag, nk, rmv, rma, Pt, out, mode);
}